// Round 4
// baseline (251.890 us; speedup 1.0000x reference)
//
#include <hip/hip_runtime.h>

#define LN_SIZE 512
#define LN_ROWS (8192 * 32)              // 262144 rows of 512 floats
#define LN_EPS 1e-5f
#define LN_SCALE 22.62741699796952f      // sqrt(512)
#define RPW 32                           // rows per wave (contiguous)

typedef float f32x4 __attribute__((ext_vector_type(4)));

// ---------------------------------------------------------------------------
// Fully fused kernel.
//   out[row][j] = (x[row]*A_j + B_j) * r(x[row]) + beta_j
//   A = (w - mean(w))*gamma, B = (b - mean(b))*gamma
//   var = c2*x^2 + c1*x + c0   (c2=512*Var(w), c1=1024*Cov(w,b), c0=512*Var(b))
//   r = sqrt(512) * rsqrt(var + eps)
// Each block redundantly reduces the 5 raw moments of (w,b) (L2-hot, 512
// elems) -> no serialized pre-kernel. Store loop is load-free and uses
// nontemporal stores (write-once stream, never re-read on device).
// ---------------------------------------------------------------------------
__global__ __launch_bounds__(256) void ln_fused_kernel(
    const float* __restrict__ x, const float* __restrict__ w,
    const float* __restrict__ b, const float* __restrict__ gamma,
    const float* __restrict__ beta, float* __restrict__ out) {
  const int tid  = (int)threadIdx.x;
  const int lane = tid & 63;
  const int wv   = tid >> 6;  // wave index within block (0..3)

  // ---- 5-moment reduction over j=0..511 (each thread: 2 elements) ----
  float sw, sb, sww, swb, sbb;
  {
    const int j0 = tid, j1 = tid + 256;
    const float w0 = w[j0], w1 = w[j1];
    const float p0 = b[j0], p1 = b[j1];
    sw  = w0 + w1;
    sb  = p0 + p1;
    sww = w0 * w0 + w1 * w1;
    swb = w0 * p0 + w1 * p1;
    sbb = p0 * p0 + p1 * p1;
  }
#pragma unroll
  for (int off = 32; off > 0; off >>= 1) {
    sw  += __shfl_xor(sw, off);
    sb  += __shfl_xor(sb, off);
    sww += __shfl_xor(sww, off);
    swb += __shfl_xor(swb, off);
    sbb += __shfl_xor(sbb, off);
  }
  __shared__ float red[4][5];
  if (lane == 0) {
    red[wv][0] = sw; red[wv][1] = sb; red[wv][2] = sww;
    red[wv][3] = swb; red[wv][4] = sbb;
  }
  __syncthreads();
  sw  = red[0][0] + red[1][0] + red[2][0] + red[3][0];
  sb  = red[0][1] + red[1][1] + red[2][1] + red[3][1];
  sww = red[0][2] + red[1][2] + red[2][2] + red[3][2];
  swb = red[0][3] + red[1][3] + red[2][3] + red[3][3];
  sbb = red[0][4] + red[1][4] + red[2][4] + red[3][4];

  const float inv_n = 1.0f / (float)LN_SIZE;
  const float mw  = sw * inv_n;
  const float mb  = sb * inv_n;
  const float Sww = sww * inv_n - mw * mw;
  const float Swb = swb * inv_n - mw * mb;
  const float Sbb = sbb * inv_n - mb * mb;
  const float c2 = (float)LN_SIZE * Sww;
  const float c1 = 2.0f * (float)LN_SIZE * Swb;
  const float c0 = (float)LN_SIZE * Sbb;

  // ---- per-lane column coefficients (8 columns per lane) ----
  const int j = lane * 8;
  const float4 wv0 = *(const float4*)(w + j);
  const float4 wv1 = *(const float4*)(w + j + 4);
  const float4 bv0 = *(const float4*)(b + j);
  const float4 bv1 = *(const float4*)(b + j + 4);
  const float4 gv0 = *(const float4*)(gamma + j);
  const float4 gv1 = *(const float4*)(gamma + j + 4);
  const float4 g0  = *(const float4*)(beta + j);
  const float4 g1  = *(const float4*)(beta + j + 4);

  float4 a0, a1, B0, B1;
  a0.x = (wv0.x - mw) * gv0.x;  a0.y = (wv0.y - mw) * gv0.y;
  a0.z = (wv0.z - mw) * gv0.z;  a0.w = (wv0.w - mw) * gv0.w;
  a1.x = (wv1.x - mw) * gv1.x;  a1.y = (wv1.y - mw) * gv1.y;
  a1.z = (wv1.z - mw) * gv1.z;  a1.w = (wv1.w - mw) * gv1.w;
  B0.x = (bv0.x - mb) * gv0.x;  B0.y = (bv0.y - mb) * gv0.y;
  B0.z = (bv0.z - mb) * gv0.z;  B0.w = (bv0.w - mb) * gv0.w;
  B1.x = (bv1.x - mb) * gv1.x;  B1.y = (bv1.y - mb) * gv1.y;
  B1.z = (bv1.z - mb) * gv1.z;  B1.w = (bv1.w - mb) * gv1.w;

  // ---- this wave's 32 contiguous rows ----
  const int wid  = (int)((blockIdx.x * blockDim.x + tid) >> 6);
  const int row0 = wid * RPW;
  if (row0 >= LN_ROWS) return;

  const float xv  = x[row0 + (lane & 31)];
  const float var = fmaf(fmaf(c2, xv, c1), xv, c0);
  const float rv  = LN_SCALE * rsqrtf(var + LN_EPS);

  float* dst = out + (size_t)row0 * LN_SIZE + j;
#pragma unroll
  for (int i = 0; i < RPW; ++i) {
    const float xi = __shfl(xv, i);
    const float ri = __shfl(rv, i);

    f32x4 o0, o1;
    o0.x = fmaf(fmaf(xi, a0.x, B0.x), ri, g0.x);
    o0.y = fmaf(fmaf(xi, a0.y, B0.y), ri, g0.y);
    o0.z = fmaf(fmaf(xi, a0.z, B0.z), ri, g0.z);
    o0.w = fmaf(fmaf(xi, a0.w, B0.w), ri, g0.w);
    o1.x = fmaf(fmaf(xi, a1.x, B1.x), ri, g1.x);
    o1.y = fmaf(fmaf(xi, a1.y, B1.y), ri, g1.y);
    o1.z = fmaf(fmaf(xi, a1.z, B1.z), ri, g1.z);
    o1.w = fmaf(fmaf(xi, a1.w, B1.w), ri, g1.w);

    __builtin_nontemporal_store(o0, (f32x4*)dst);
    __builtin_nontemporal_store(o1, (f32x4*)(dst + 4));
    dst += LN_SIZE;
  }
}

extern "C" void kernel_launch(void* const* d_in, const int* in_sizes, int n_in,
                              void* d_out, int out_size, void* d_ws, size_t ws_size,
                              hipStream_t stream) {
  const float* x     = (const float*)d_in[0];
  const float* w     = (const float*)d_in[1];
  const float* b     = (const float*)d_in[2];
  const float* gamma = (const float*)d_in[3];
  const float* beta  = (const float*)d_in[4];
  float* out = (float*)d_out;
  (void)d_ws; (void)ws_size;

  // 2048 blocks x 256 threads = 8192 waves (exactly 256 CU x 32 waves);
  // 262144 rows / 32 rows-per-wave.
  ln_fused_kernel<<<2048, 256, 0, stream>>>(x, w, b, gamma, beta, out);
}

// Round 5
// 100.647 us; speedup vs baseline: 2.5027x; 2.5027x over previous
//
#include <hip/hip_runtime.h>

#define LN_SIZE 512
#define LN_ROWS (8192 * 32)              // 262144 rows of 512 floats
#define LN_EPS 1e-5f
#define LN_SCALE 22.62741699796952f      // sqrt(512)
#define RPW 32                           // rows per wave (contiguous)

typedef float f32x4 __attribute__((ext_vector_type(4)));

// ---------------------------------------------------------------------------
// Fully fused kernel.
//   out[row][j] = (x[row]*A_j + B_j) * r(x[row]) + beta_j
//   A = (w - mean(w))*gamma, B = (b - mean(b))*gamma
//   var = c2*x^2 + c1*x + c0   (c2=512*Var(w), c1=1024*Cov(w,b), c0=512*Var(b))
//   r = sqrt(512) * rsqrt(var + eps)
// Each block redundantly reduces the 5 raw moments of (w,b) (L2-hot, 512
// elems) -> no serialized pre-kernel, no second launch. Store loop is
// load-free; PLAIN cached stores (nt stores measured 2.3x slower on gfx950 —
// they defeat L2 write combining; see R4 post-mortem).
// ---------------------------------------------------------------------------
__global__ __launch_bounds__(256) void ln_fused_kernel(
    const float* __restrict__ x, const float* __restrict__ w,
    const float* __restrict__ b, const float* __restrict__ gamma,
    const float* __restrict__ beta, float* __restrict__ out) {
  const int tid  = (int)threadIdx.x;
  const int lane = tid & 63;
  const int wv   = tid >> 6;  // wave index within block (0..3)

  // ---- 5-moment reduction over j=0..511 (each thread: 2 elements) ----
  float sw, sb, sww, swb, sbb;
  {
    const int j0 = tid, j1 = tid + 256;
    const float w0 = w[j0], w1 = w[j1];
    const float p0 = b[j0], p1 = b[j1];
    sw  = w0 + w1;
    sb  = p0 + p1;
    sww = w0 * w0 + w1 * w1;
    swb = w0 * p0 + w1 * p1;
    sbb = p0 * p0 + p1 * p1;
  }
#pragma unroll
  for (int off = 32; off > 0; off >>= 1) {
    sw  += __shfl_xor(sw, off);
    sb  += __shfl_xor(sb, off);
    sww += __shfl_xor(sww, off);
    swb += __shfl_xor(swb, off);
    sbb += __shfl_xor(sbb, off);
  }
  __shared__ float red[4][5];
  if (lane == 0) {
    red[wv][0] = sw; red[wv][1] = sb; red[wv][2] = sww;
    red[wv][3] = swb; red[wv][4] = sbb;
  }
  __syncthreads();
  sw  = red[0][0] + red[1][0] + red[2][0] + red[3][0];
  sb  = red[0][1] + red[1][1] + red[2][1] + red[3][1];
  sww = red[0][2] + red[1][2] + red[2][2] + red[3][2];
  swb = red[0][3] + red[1][3] + red[2][3] + red[3][3];
  sbb = red[0][4] + red[1][4] + red[2][4] + red[3][4];

  const float inv_n = 1.0f / (float)LN_SIZE;
  const float mw  = sw * inv_n;
  const float mb  = sb * inv_n;
  const float Sww = sww * inv_n - mw * mw;
  const float Swb = swb * inv_n - mw * mb;
  const float Sbb = sbb * inv_n - mb * mb;
  const float c2 = (float)LN_SIZE * Sww;
  const float c1 = 2.0f * (float)LN_SIZE * Swb;
  const float c0 = (float)LN_SIZE * Sbb;

  // ---- per-lane column coefficients (8 columns per lane) ----
  const int j = lane * 8;
  const float4 wv0 = *(const float4*)(w + j);
  const float4 wv1 = *(const float4*)(w + j + 4);
  const float4 bv0 = *(const float4*)(b + j);
  const float4 bv1 = *(const float4*)(b + j + 4);
  const float4 gv0 = *(const float4*)(gamma + j);
  const float4 gv1 = *(const float4*)(gamma + j + 4);
  const float4 g0  = *(const float4*)(beta + j);
  const float4 g1  = *(const float4*)(beta + j + 4);

  float4 a0, a1, B0, B1;
  a0.x = (wv0.x - mw) * gv0.x;  a0.y = (wv0.y - mw) * gv0.y;
  a0.z = (wv0.z - mw) * gv0.z;  a0.w = (wv0.w - mw) * gv0.w;
  a1.x = (wv1.x - mw) * gv1.x;  a1.y = (wv1.y - mw) * gv1.y;
  a1.z = (wv1.z - mw) * gv1.z;  a1.w = (wv1.w - mw) * gv1.w;
  B0.x = (bv0.x - mb) * gv0.x;  B0.y = (bv0.y - mb) * gv0.y;
  B0.z = (bv0.z - mb) * gv0.z;  B0.w = (bv0.w - mb) * gv0.w;
  B1.x = (bv1.x - mb) * gv1.x;  B1.y = (bv1.y - mb) * gv1.y;
  B1.z = (bv1.z - mb) * gv1.z;  B1.w = (bv1.w - mb) * gv1.w;

  // ---- this wave's 32 contiguous rows ----
  const int wid  = (int)((blockIdx.x * blockDim.x + tid) >> 6);
  const int row0 = wid * RPW;
  if (row0 >= LN_ROWS) return;

  const float xv  = x[row0 + (lane & 31)];
  const float var = fmaf(fmaf(c2, xv, c1), xv, c0);
  const float rv  = LN_SCALE * rsqrtf(var + LN_EPS);

  float* dst = out + (size_t)row0 * LN_SIZE + j;
#pragma unroll
  for (int i = 0; i < RPW; ++i) {
    const float xi = __shfl(xv, i);
    const float ri = __shfl(rv, i);

    f32x4 o0, o1;
    o0.x = fmaf(fmaf(xi, a0.x, B0.x), ri, g0.x);
    o0.y = fmaf(fmaf(xi, a0.y, B0.y), ri, g0.y);
    o0.z = fmaf(fmaf(xi, a0.z, B0.z), ri, g0.z);
    o0.w = fmaf(fmaf(xi, a0.w, B0.w), ri, g0.w);
    o1.x = fmaf(fmaf(xi, a1.x, B1.x), ri, g1.x);
    o1.y = fmaf(fmaf(xi, a1.y, B1.y), ri, g1.y);
    o1.z = fmaf(fmaf(xi, a1.z, B1.z), ri, g1.z);
    o1.w = fmaf(fmaf(xi, a1.w, B1.w), ri, g1.w);

    *(f32x4*)(dst)     = o0;
    *(f32x4*)(dst + 4) = o1;
    dst += LN_SIZE;
  }
}

extern "C" void kernel_launch(void* const* d_in, const int* in_sizes, int n_in,
                              void* d_out, int out_size, void* d_ws, size_t ws_size,
                              hipStream_t stream) {
  const float* x     = (const float*)d_in[0];
  const float* w     = (const float*)d_in[1];
  const float* b     = (const float*)d_in[2];
  const float* gamma = (const float*)d_in[3];
  const float* beta  = (const float*)d_in[4];
  float* out = (float*)d_out;
  (void)d_ws; (void)ws_size;

  // 2048 blocks x 256 threads = 8192 waves (exactly 256 CU x 32 waves);
  // 262144 rows / 32 rows-per-wave.
  ln_fused_kernel<<<2048, 256, 0, stream>>>(x, w, b, gamma, beta, out);
}